// Round 18
// baseline (962.418 us; speedup 1.0000x reference)
//
#include <hip/hip_runtime.h>
#include <math.h>
#include <type_traits>

// ---------- bf16 helpers (intermediate buffers only; I/O is fp32) ----------

__device__ __forceinline__ float bf2f(unsigned short u) {
    union { unsigned int i; float f; } v; v.i = ((unsigned int)u) << 16; return v.f;
}
__device__ __forceinline__ unsigned short f2bf(float f) {
    union { float f_; unsigned int i; } v; v.f_ = f;
    unsigned int x = v.i;
    return (unsigned short)((x + 0x7fffu + ((x >> 16) & 1u)) >> 16);  // RNE
}
__device__ __forceinline__ float sigm(float x) { return 1.f / (1.f + expf(-x)); }

typedef __attribute__((ext_vector_type(8))) short short8;
typedef __attribute__((ext_vector_type(16))) float f32x16;

// ---------------- fused init ----------------

__global__ void k_init(int* __restrict__ indeg, int* __restrict__ cursor,
                       int* __restrict__ gstart, int* __restrict__ gend,
                       float* __restrict__ pooled, int N) {
    int i = blockIdx.x * 256 + threadIdx.x;
    if (i < N) indeg[i] = 0;
    else if (i < 2 * N) cursor[i - N] = 0;
    else if (i < 2 * N + 64) gstart[i - 2 * N] = 0;
    else if (i < 2 * N + 128) gend[i - 2 * N - 64] = 0;
    else if (i < 2 * N + 128 + 64 * 512) pooled[i - 2 * N - 128] = 0.f;
}

// ---------------- weight prep: fragment-major Wf for 32x32x16 MFMA ----------------

template <int K, int NC>
__device__ __forceinline__ void prep_elem(const float* __restrict__ W,
                                          unsigned short* __restrict__ Wf, int idx) {
    constexpr int S = K / 16;
    int lane = idx & 63;
    int ts = idx >> 6;
    int s = ts % S, t = ts / S;
    int n = t * 32 + (lane & 31);
    int kb = s * 16 + (lane >> 5) * 8;
    short8 o;
    #pragma unroll
    for (int j = 0; j < 8; ++j) o[j] = (short)f2bf(W[(size_t)(kb + j) * NC + n]);
    *(short8*)(Wf + (size_t)idx * 8) = o;
}

__global__ void k_count(const int* __restrict__ dst, int* __restrict__ indeg, int E,
                        const float* __restrict__ W1, unsigned short* __restrict__ Wf1,
                        const float* __restrict__ W2, unsigned short* __restrict__ Wf2,
                        const float* __restrict__ W3, unsigned short* __restrict__ Wf3) {
    constexpr int P1 = 32 * 128 / 8, P2 = 128 * 256 / 8, P3 = 256 * 512 / 8;
    int i = blockIdx.x * 256 + threadIdx.x;
    if (i < E) atomicAdd(&indeg[dst[i]], 1);
    if (i < P1) prep_elem<32, 128>(W1, Wf1, i);
    else if (i < P1 + P2) prep_elem<128, 256>(W2, Wf2, i - P1);
    else if (i < P1 + P2 + P3) prep_elem<256, 512>(W3, Wf3, i - P1 - P2);
}

// ---------------- scan + dinv / + bounds ----------------

__global__ __launch_bounds__(1024) void k_scan1(const int* __restrict__ in, int* __restrict__ out,
                                                int* __restrict__ bsum, float* __restrict__ dinv,
                                                int N) {
    __shared__ int sd[1024];
    int tid = threadIdx.x;
    int i = blockIdx.x * 1024 + tid;
    int v = (i < N) ? in[i] : 0;
    if (i < N) dinv[i] = rsqrtf((float)v + 1.0f);
    sd[tid] = v;
    __syncthreads();
    for (int s = 1; s < 1024; s <<= 1) {
        int t = (tid >= s) ? sd[tid - s] : 0;
        __syncthreads();
        sd[tid] += t;
        __syncthreads();
    }
    if (i < N) out[i] = sd[tid] - v;
    if (tid == 1023) bsum[blockIdx.x] = sd[1023];
}

// parallel block-sum scan (nb <= 256)
__global__ __launch_bounds__(256) void k_scan2(int* __restrict__ bsum, int nb) {
    __shared__ int sd[256];
    int tid = threadIdx.x;
    int v = (tid < nb) ? bsum[tid] : 0;
    sd[tid] = v;
    __syncthreads();
    for (int s = 1; s < 256; s <<= 1) {
        int t = (tid >= s) ? sd[tid - s] : 0;
        __syncthreads();
        sd[tid] += t;
        __syncthreads();
    }
    if (tid < nb) bsum[tid] = sd[tid] - v;   // exclusive
    if (tid == 0) bsum[nb] = sd[255];        // total
}

__global__ __launch_bounds__(1024) void k_scan3(int* __restrict__ off, const int* __restrict__ bsum,
                                                const int* __restrict__ batch,
                                                int* __restrict__ gstart, int* __restrict__ gend,
                                                int N, int nb) {
    int i = blockIdx.x * 1024 + threadIdx.x;
    if (i < N) {
        off[i] += bsum[i >> 10];
        int g = batch[i];
        if (i == 0 || batch[i - 1] != g) gstart[g] = i;
        if (i == N - 1 || batch[i + 1] != g) gend[g] = i + 1;
    } else if (i == N) {
        off[N] = bsum[nb];
    }
}

// packed edge records: cpack[p] = {src, bits(dinv[src]*dinv[dst])} — ONE 8-B
// scattered store per edge (was two 4-B stores to two arrays)
__global__ void k_fill(const int* __restrict__ src, const int* __restrict__ dst,
                       const float* __restrict__ dinv, const int* __restrict__ off,
                       int* __restrict__ cursor, int2* __restrict__ cpack, int E) {
    int i = blockIdx.x * 256 + threadIdx.x;
    if (i >= E) return;
    int d = dst[i], s = src[i];
    int p = off[d] + atomicAdd(&cursor[d], 1);
    int2 rec; rec.x = s; rec.y = __float_as_int(dinv[s] * dinv[d]);
    cpack[p] = rec;
}

// ---------------- aggregation (R9/R11 structure, cpack metadata) ----------------

template <int F, typename T>
__device__ __forceinline__ void agg_body(
        const T* __restrict__ Hin, const float* __restrict__ dinv,
        const int* __restrict__ off, const int2* __restrict__ cpack,
        unsigned short* __restrict__ out, int N) {
    constexpr int R = (F >= 256) ? 4 : (F >= 128 ? 2 : 1);
    int wave = (int)((blockIdx.x * 256u + threadIdx.x) >> 6);
    int lane = threadIdx.x & 63;
    if (wave >= N) return;
    int fb = (F >= 64) ? lane * R : lane;
    bool act = fb < F;
    int s0 = off[wave], s1 = off[wave + 1];
    float dn = dinv[wave], sn = dn * dn;
    float acc[R];
    #pragma unroll
    for (int j = 0; j < R; ++j) acc[j] = 0.f;
    if (act) {
        const T* ps = Hin + (size_t)wave * F + fb;
        if constexpr (std::is_same_v<T, float>) {
            acc[0] = ps[0] * sn;
        } else if constexpr (R == 4) {
            ushort4 hv = *(const ushort4*)ps;
            acc[0] = bf2f(hv.x) * sn; acc[1] = bf2f(hv.y) * sn;
            acc[2] = bf2f(hv.z) * sn; acc[3] = bf2f(hv.w) * sn;
        } else {
            ushort2 hv = *(const ushort2*)ps;
            acc[0] = bf2f(hv.x) * sn; acc[1] = bf2f(hv.y) * sn;
        }
    }
    int last = s1 - 1;
    for (int e = s0; e < s1; e += 8) {
        int   idx[8];
        float wgt[8];
        #pragma unroll
        for (int j = 0; j < 8; ++j) {
            int ee = e + j;
            int ec = ee <= last ? ee : last;
            int2 m = cpack[ec];
            idx[j] = m.x;
            wgt[j] = (ee <= last) ? __int_as_float(m.y) : 0.f;
        }
        if (act) {
            if constexpr (std::is_same_v<T, float>) {
                float d0[8];
                #pragma unroll
                for (int j = 0; j < 8; ++j) d0[j] = Hin[(size_t)idx[j] * F + fb];
                #pragma unroll
                for (int j = 0; j < 8; ++j) acc[0] += d0[j] * wgt[j];
            } else if constexpr (R == 4) {
                ushort4 d0[8];
                #pragma unroll
                for (int j = 0; j < 8; ++j)
                    d0[j] = *(const ushort4*)(Hin + (size_t)idx[j] * F + fb);
                #pragma unroll
                for (int j = 0; j < 8; ++j) {
                    float w = wgt[j];
                    acc[0] += bf2f(d0[j].x) * w; acc[1] += bf2f(d0[j].y) * w;
                    acc[2] += bf2f(d0[j].z) * w; acc[3] += bf2f(d0[j].w) * w;
                }
            } else {
                ushort2 d0[8];
                #pragma unroll
                for (int j = 0; j < 8; ++j)
                    d0[j] = *(const ushort2*)(Hin + (size_t)idx[j] * F + fb);
                #pragma unroll
                for (int j = 0; j < 8; ++j) {
                    float w = wgt[j];
                    acc[0] += bf2f(d0[j].x) * w; acc[1] += bf2f(d0[j].y) * w;
                }
            }
        }
    }
    if (act) {
        unsigned short* pd = out + (size_t)wave * F + fb;
        if constexpr (R == 4) {
            ushort4 o; o.x = f2bf(acc[0]); o.y = f2bf(acc[1]);
            o.z = f2bf(acc[2]); o.w = f2bf(acc[3]);
            *(ushort4*)pd = o;
        } else if constexpr (R == 2) {
            ushort2 o; o.x = f2bf(acc[0]); o.y = f2bf(acc[1]);
            *(ushort2*)pd = o;
        } else {
            pd[0] = f2bf(acc[0]);
        }
    }
}

__global__ __launch_bounds__(256) void k_aggL1(
        const float* __restrict__ Hin, const float* __restrict__ dinv,
        const int* __restrict__ off, const int2* __restrict__ cpack,
        unsigned short* __restrict__ out, int N) {
    agg_body<32, float>(Hin, dinv, off, cpack, out, N);
}

__global__ __launch_bounds__(256) void k_aggL2(
        const unsigned short* __restrict__ Hin, const float* __restrict__ dinv,
        const int* __restrict__ off, const int2* __restrict__ cpack,
        unsigned short* __restrict__ out, int N) {
    agg_body<128, unsigned short>(Hin, dinv, off, cpack, out, N);
}

__global__ __launch_bounds__(256) void k_aggL3pair(
        const unsigned short* __restrict__ Hin, const float* __restrict__ dinv,
        const int* __restrict__ off, const int2* __restrict__ cpack,
        unsigned short* __restrict__ out, int N) {
    constexpr int F = 256;
    int wave = (int)((blockIdx.x * 256u + threadIdx.x) >> 6);
    int lane = threadIdx.x & 63;
    if (wave >= N) return;
    int half = lane >> 5;
    int fb = (lane & 31) * 8;
    int s0 = off[wave], s1 = off[wave + 1];
    int last = s1 - 1;
    float acc[8];
    #pragma unroll
    for (int k = 0; k < 8; ++k) acc[k] = 0.f;

    for (int e = s0; e < s1; e += 16) {
        int   idx[8];
        float wgt[8];
        #pragma unroll
        for (int j = 0; j < 8; ++j) {
            int ee = e + j * 2 + half;
            int ec = ee <= last ? ee : last;
            int2 m = cpack[ec];
            idx[j] = m.x;
            wgt[j] = (ee <= last) ? __int_as_float(m.y) : 0.f;
        }
        short8 d0[8];
        #pragma unroll
        for (int j = 0; j < 8; ++j)
            d0[j] = *(const short8*)(Hin + (size_t)idx[j] * F + fb);
        #pragma unroll
        for (int j = 0; j < 8; ++j) {
            float w = wgt[j];
            #pragma unroll
            for (int k = 0; k < 8; ++k)
                acc[k] += bf2f((unsigned short)d0[j][k]) * w;
        }
    }
    #pragma unroll
    for (int k = 0; k < 8; ++k) acc[k] += __shfl_xor(acc[k], 32, 64);

    if (half == 0) {
        float dn = dinv[wave], sn = dn * dn;
        short8 selfv = *(const short8*)(Hin + (size_t)wave * F + fb);
        short8 o;
        #pragma unroll
        for (int k = 0; k < 8; ++k)
            o[k] = (short)f2bf(acc[k] + bf2f((unsigned short)selfv[k]) * sn);
        *(short8*)(out + (size_t)wave * F + fb) = o;
    }
}

// ---------------- MFMA GEMM (R17-proven): LDS-staged A (swizzled), coalesced B ----

template <int K, int NC, int POOL>
__device__ __forceinline__ void gemm_body(
        const unsigned short* __restrict__ A, const unsigned short* __restrict__ Wf,
        const float* __restrict__ bias, unsigned short* __restrict__ C,
        float* __restrict__ pooled, const int* __restrict__ batch, int M) {
    constexpr int S = K / 16;
    constexpr int CPR = K / 8;
    constexpr int NT = NC / 32;
    __shared__ unsigned short sA[64 * K];
    __shared__ float pacc[POOL ? 2 : 1][POOL ? NC : 1];
    __shared__ int sbat[POOL ? 64 : 1];
    int tid = threadIdx.x, lane = tid & 63, w = tid >> 6;
    int q = lane >> 5, m = lane & 31;
    int row0 = blockIdx.x * 64;

    if (POOL) {
        if (tid < 64) { int rr = row0 + tid; if (rr > M - 1) rr = M - 1; sbat[tid] = batch[rr]; }
        for (int i = tid; i < 2 * NC; i += 256) pacc[i / NC][i % NC] = 0.f;
    }

    #pragma unroll
    for (int i = 0; i < (64 * CPR) / 256; ++i) {
        int g = i * 256 + tid;
        int mm = g / CPR, kc = g % CPR;
        int grow = row0 + mm; if (grow > M - 1) grow = M - 1;
        short8 v = *(const short8*)(A + (size_t)grow * K + kc * 8);
        int xm = (CPR >= 8) ? (mm & 7) : ((mm >> 1) & 3);
        *(short8*)(sA + (size_t)(mm * CPR + (kc ^ xm)) * 8) = v;
    }
    __syncthreads();

    int gmin = 0; bool fast = false;
    if (POOL) { gmin = sbat[0]; fast = (sbat[63] - gmin) <= 1; }

    const short8* Wf8 = (const short8*)Wf;
    for (int t = w; t < NT; t += 4) {
        short8 bF[S];
        #pragma unroll
        for (int s = 0; s < S; ++s) bF[s] = Wf8[(t * S + s) * 64 + lane];
        int colBase = t * 32 + m;
        float bv = bias[colBase];
        #pragma unroll
        for (int half = 0; half < 2; ++half) {
            int mrow = half * 32 + m;
            int xm = (CPR >= 8) ? (mrow & 7) : ((mrow >> 1) & 3);
            f32x16 acc;
            #pragma unroll
            for (int j = 0; j < 16; ++j) acc[j] = 0.f;
            #pragma unroll
            for (int s = 0; s < S; ++s) {
                int kc = s * 2 + q;
                short8 aF = *(const short8*)(sA + (size_t)(mrow * CPR + (kc ^ xm)) * 8);
                acc = __builtin_amdgcn_mfma_f32_32x32x16_bf16(aF, bF[s], acc, 0, 0, 0);
            }
            #pragma unroll
            for (int j = 0; j < 16; ++j) {
                int rloc = half * 32 + (j & 3) + 8 * (j >> 2) + 4 * q;
                int row = row0 + rloc;
                if (row < M) {
                    float v = fmaxf(acc[j] + bv, 0.f);
                    if (POOL) {
                        int g = sbat[rloc];
                        if (fast) atomicAdd(&pacc[g - gmin][colBase], v);
                        else      atomicAdd(&pooled[(size_t)g * NC + colBase], v);
                    } else {
                        C[(size_t)row * NC + colBase] = f2bf(v);
                    }
                }
            }
        }
    }
    if (POOL) {
        __syncthreads();
        if (fast) {
            for (int i = tid; i < 2 * NC; i += 256) {
                int gg = i / NC, cl = i % NC;
                if (gmin + gg < 64)
                    atomicAdd(&pooled[(size_t)(gmin + gg) * NC + cl], pacc[gg][cl]);
            }
        }
    }
}

__global__ __launch_bounds__(256, 2) void k_gemmL1(
        const unsigned short* __restrict__ A, const unsigned short* __restrict__ Wf,
        const float* __restrict__ bias, unsigned short* __restrict__ C, int M) {
    gemm_body<32, 128, 0>(A, Wf, bias, C, nullptr, nullptr, M);
}

__global__ __launch_bounds__(256, 2) void k_gemmL2(
        const unsigned short* __restrict__ A, const unsigned short* __restrict__ Wf,
        const float* __restrict__ bias, unsigned short* __restrict__ C, int M) {
    gemm_body<128, 256, 0>(A, Wf, bias, C, nullptr, nullptr, M);
}

__global__ __launch_bounds__(256, 2) void k_gemmL3pool(
        const unsigned short* __restrict__ A, const unsigned short* __restrict__ Wf,
        const float* __restrict__ bias, float* __restrict__ pooled,
        const int* __restrict__ batch, int M) {
    gemm_body<256, 512, 1>(A, Wf, bias, nullptr, pooled, batch, M);
}

// ---------------- fused head: template-unrolled dots, 4-way partial sums ----------------

template <int K>
__device__ __forceinline__ float dotT(const float* __restrict__ w, const float* __restrict__ x) {
    float a0 = 0.f, a1 = 0.f, a2 = 0.f, a3 = 0.f;
    #pragma unroll
    for (int k = 0; k < K; k += 16) {
        float4 w0 = *(const float4*)(w + k);
        float4 w1 = *(const float4*)(w + k + 4);
        float4 w2 = *(const float4*)(w + k + 8);
        float4 w3 = *(const float4*)(w + k + 12);
        a0 += w0.x * x[k]      + w0.y * x[k + 1]  + w0.z * x[k + 2]  + w0.w * x[k + 3];
        a1 += w1.x * x[k + 4]  + w1.y * x[k + 5]  + w1.z * x[k + 6]  + w1.w * x[k + 7];
        a2 += w2.x * x[k + 8]  + w2.y * x[k + 9]  + w2.z * x[k + 10] + w2.w * x[k + 11];
        a3 += w3.x * x[k + 12] + w3.y * x[k + 13] + w3.z * x[k + 14] + w3.w * x[k + 15];
    }
    return (a0 + a1) + (a2 + a3);
}

__global__ __launch_bounds__(256) void k_head(
        const float* __restrict__ pooledSum,
        const int* __restrict__ gstart, const int* __restrict__ gend,
        const float* __restrict__ Wih0, const float* __restrict__ bih0,
        const float* __restrict__ bhh0,
        const float* __restrict__ Wih1, const float* __restrict__ bih1,
        const float* __restrict__ bhh1,
        const float* __restrict__ Wp, const float* __restrict__ bp,
        float* __restrict__ out) {
    __shared__ float sx[512];
    __shared__ float sh[256];
    int g = blockIdx.x, tid = threadIdx.x;
    float cnt = (float)(gend[g] - gstart[g]);
    float inv = 1.f / fmaxf(cnt, 1.f);
    sx[tid]       = pooledSum[g * 512 + tid] * inv;
    sx[tid + 256] = pooledSum[g * 512 + 256 + tid] * inv;
    __syncthreads();

    float ai = bih0[tid]       + bhh0[tid]       + dotT<512>(Wih0 + (size_t)tid * 512, sx);
    float ag = bih0[tid + 512] + bhh0[tid + 512] + dotT<512>(Wih0 + (size_t)(tid + 512) * 512, sx);
    float ao = bih0[tid + 768] + bhh0[tid + 768] + dotT<512>(Wih0 + (size_t)(tid + 768) * 512, sx);
    float c0 = sigm(ai) * tanhf(ag);
    float h1 = sigm(ao) * tanhf(c0);
    __syncthreads();
    sh[tid] = h1;
    __syncthreads();

    ai = bih1[tid]       + bhh1[tid]       + dotT<256>(Wih1 + (size_t)tid * 256, sh);
    ag = bih1[tid + 512] + bhh1[tid + 512] + dotT<256>(Wih1 + (size_t)(tid + 512) * 256, sh);
    ao = bih1[tid + 768] + bhh1[tid + 768] + dotT<256>(Wih1 + (size_t)(tid + 768) * 256, sh);
    float c1 = sigm(ai) * tanhf(ag);
    float h2 = sigm(ao) * tanhf(c1);
    __syncthreads();
    sx[tid] = h2;
    __syncthreads();

    float o0 = bp[tid]       + dotT<256>(Wp + (size_t)tid * 256, sx);
    float o1 = bp[tid + 256] + dotT<256>(Wp + (size_t)(tid + 256) * 256, sx);
    out[g * 512 + tid]       = o0;
    out[g * 512 + 256 + tid] = o1;
}

// ---------------- launch ----------------

extern "C" void kernel_launch(void* const* d_in, const int* in_sizes, int n_in,
                              void* d_out, int out_size, void* d_ws, size_t ws_size,
                              hipStream_t stream) {
    const float* x     = (const float*)d_in[0];
    const int*   eidx  = (const int*)d_in[1];
    const int*   batch = (const int*)d_in[2];
    const float* W1 = (const float*)d_in[3];  const float* b1 = (const float*)d_in[4];
    const float* W2 = (const float*)d_in[5];  const float* b2 = (const float*)d_in[6];
    const float* W3 = (const float*)d_in[7];  const float* b3 = (const float*)d_in[8];
    const float* Wih0 = (const float*)d_in[9];
    const float* bih0 = (const float*)d_in[11];
    const float* bhh0 = (const float*)d_in[12];
    const float* Wih1 = (const float*)d_in[13];
    const float* bih1 = (const float*)d_in[15];
    const float* bhh1 = (const float*)d_in[16];
    const float* Wp = (const float*)d_in[17]; const float* bp = (const float*)d_in[18];
    float* out = (float*)d_out;

    const int N = in_sizes[0] / 32;
    const int E = in_sizes[1] / 2;
    const int* src = eidx;
    const int* dst = eidx + E;
    const int rowTiles = (N + 63) / 64;

    char* w = (char*)d_ws;
    auto alloc = [&](size_t bytes) {
        char* p = w;
        w += (bytes + 255) & ~(size_t)255;
        return p;
    };
    unsigned short* buf1 = (unsigned short*)alloc((size_t)N * 256 * 2);
    unsigned short* buf2 = (unsigned short*)alloc((size_t)N * 256 * 2);
    unsigned short* Wf1  = (unsigned short*)alloc(128 * 32 * 2);
    unsigned short* Wf2  = (unsigned short*)alloc(256 * 128 * 2);
    unsigned short* Wf3  = (unsigned short*)alloc(512 * 256 * 2);
    int*   indeg  = (int*)alloc((size_t)N * 4);
    int*   off    = (int*)alloc((size_t)(N + 1) * 4);
    int*   cursor = (int*)alloc((size_t)N * 4);
    float* dinv   = (float*)alloc((size_t)N * 4);
    int2*  cpack  = (int2*)alloc((size_t)E * 8);
    int*   bsum   = (int*)alloc(300 * 4);
    int*   gstart = (int*)alloc(64 * 4);
    int*   gend   = (int*)alloc(64 * 4);
    float* pooled = (float*)alloc(64 * 512 * 4);

    int initTot = 2 * N + 128 + 64 * 512;
    k_init<<<(initTot + 255) / 256, 256, 0, stream>>>(indeg, cursor, gstart, gend, pooled, N);
    k_count<<<(E + 255) / 256, 256, 0, stream>>>(dst, indeg, E, W1, Wf1, W2, Wf2, W3, Wf3);
    int nb = (N + 1023) / 1024;
    k_scan1<<<nb, 1024, 0, stream>>>(indeg, off, bsum, dinv, N);
    k_scan2<<<1, 256, 0, stream>>>(bsum, nb);
    k_scan3<<<(N + 1 + 1023) / 1024, 1024, 0, stream>>>(off, bsum, batch, gstart, gend, N, nb);
    k_fill<<<(E + 255) / 256, 256, 0, stream>>>(src, dst, dinv, off, cursor, cpack, E);

    int aggBlocks = (N + 3) / 4;

    k_aggL1<<<aggBlocks, 256, 0, stream>>>(x, dinv, off, cpack, buf1, N);
    k_gemmL1<<<rowTiles, 256, 0, stream>>>(buf1, Wf1, b1, buf2, N);
    k_aggL2<<<aggBlocks, 256, 0, stream>>>(buf2, dinv, off, cpack, buf1, N);
    k_gemmL2<<<rowTiles, 256, 0, stream>>>(buf1, Wf2, b2, buf2, N);
    k_aggL3pair<<<aggBlocks, 256, 0, stream>>>(buf2, dinv, off, cpack, buf1, N);
    k_gemmL3pool<<<rowTiles, 256, 0, stream>>>(buf1, Wf3, b3, pooled, batch, N);

    k_head<<<64, 256, 0, stream>>>(pooled, gstart, gend,
                                   Wih0, bih0, bhh0, Wih1, bih1, bhh1, Wp, bp, out);
}

// Round 19
// 822.635 us; speedup vs baseline: 1.1699x; 1.1699x over previous
//
#include <hip/hip_runtime.h>
#include <math.h>
#include <type_traits>

// ---------- bf16 helpers (intermediate buffers only; I/O is fp32) ----------

__device__ __forceinline__ float bf2f(unsigned short u) {
    union { unsigned int i; float f; } v; v.i = ((unsigned int)u) << 16; return v.f;
}
__device__ __forceinline__ unsigned short f2bf(float f) {
    union { float f_; unsigned int i; } v; v.f_ = f;
    unsigned int x = v.i;
    return (unsigned short)((x + 0x7fffu + ((x >> 16) & 1u)) >> 16);  // RNE
}
__device__ __forceinline__ float sigm(float x) { return 1.f / (1.f + expf(-x)); }

typedef __attribute__((ext_vector_type(8))) short short8;
typedef __attribute__((ext_vector_type(16))) float f32x16;

// ---------------- fused init ----------------

__global__ void k_init(int* __restrict__ indeg, int* __restrict__ cursor,
                       int* __restrict__ gstart, int* __restrict__ gend,
                       float* __restrict__ pooled, int N) {
    int i = blockIdx.x * 256 + threadIdx.x;
    if (i < N) indeg[i] = 0;
    else if (i < 2 * N) cursor[i - N] = 0;
    else if (i < 2 * N + 64) gstart[i - 2 * N] = 0;
    else if (i < 2 * N + 128) gend[i - 2 * N - 64] = 0;
    else if (i < 2 * N + 128 + 64 * 512) pooled[i - 2 * N - 128] = 0.f;
}

// ---------------- weight prep: fragment-major Wf for 32x32x16 MFMA ----------------

template <int K, int NC>
__device__ __forceinline__ void prep_elem(const float* __restrict__ W,
                                          unsigned short* __restrict__ Wf, int idx) {
    constexpr int S = K / 16;
    int lane = idx & 63;
    int ts = idx >> 6;
    int s = ts % S, t = ts / S;
    int n = t * 32 + (lane & 31);
    int kb = s * 16 + (lane >> 5) * 8;
    short8 o;
    #pragma unroll
    for (int j = 0; j < 8; ++j) o[j] = (short)f2bf(W[(size_t)(kb + j) * NC + n]);
    *(short8*)(Wf + (size_t)idx * 8) = o;
}

__global__ void k_count(const int* __restrict__ dst, int* __restrict__ indeg, int E,
                        const float* __restrict__ W1, unsigned short* __restrict__ Wf1,
                        const float* __restrict__ W2, unsigned short* __restrict__ Wf2,
                        const float* __restrict__ W3, unsigned short* __restrict__ Wf3) {
    constexpr int P1 = 32 * 128 / 8, P2 = 128 * 256 / 8, P3 = 256 * 512 / 8;
    int i = blockIdx.x * 256 + threadIdx.x;
    if (i < E) atomicAdd(&indeg[dst[i]], 1);
    if (i < P1) prep_elem<32, 128>(W1, Wf1, i);
    else if (i < P1 + P2) prep_elem<128, 256>(W2, Wf2, i - P1);
    else if (i < P1 + P2 + P3) prep_elem<256, 512>(W3, Wf3, i - P1 - P2);
}

// ---------------- scan + dinv / + bounds ----------------

__global__ __launch_bounds__(1024) void k_scan1(const int* __restrict__ in, int* __restrict__ out,
                                                int* __restrict__ bsum, float* __restrict__ dinv,
                                                int N) {
    __shared__ int sd[1024];
    int tid = threadIdx.x;
    int i = blockIdx.x * 1024 + tid;
    int v = (i < N) ? in[i] : 0;
    if (i < N) dinv[i] = rsqrtf((float)v + 1.0f);
    sd[tid] = v;
    __syncthreads();
    for (int s = 1; s < 1024; s <<= 1) {
        int t = (tid >= s) ? sd[tid - s] : 0;
        __syncthreads();
        sd[tid] += t;
        __syncthreads();
    }
    if (i < N) out[i] = sd[tid] - v;
    if (tid == 1023) bsum[blockIdx.x] = sd[1023];
}

// parallel block-sum scan (nb <= 256)
__global__ __launch_bounds__(256) void k_scan2(int* __restrict__ bsum, int nb) {
    __shared__ int sd[256];
    int tid = threadIdx.x;
    int v = (tid < nb) ? bsum[tid] : 0;
    sd[tid] = v;
    __syncthreads();
    for (int s = 1; s < 256; s <<= 1) {
        int t = (tid >= s) ? sd[tid - s] : 0;
        __syncthreads();
        sd[tid] += t;
        __syncthreads();
    }
    if (tid < nb) bsum[tid] = sd[tid] - v;   // exclusive
    if (tid == 0) bsum[nb] = sd[255];        // total
}

__global__ __launch_bounds__(1024) void k_scan3(int* __restrict__ off, const int* __restrict__ bsum,
                                                const int* __restrict__ batch,
                                                int* __restrict__ gstart, int* __restrict__ gend,
                                                int N, int nb) {
    int i = blockIdx.x * 1024 + threadIdx.x;
    if (i < N) {
        off[i] += bsum[i >> 10];
        int g = batch[i];
        if (i == 0 || batch[i - 1] != g) gstart[g] = i;
        if (i == N - 1 || batch[i + 1] != g) gend[g] = i + 1;
    } else if (i == N) {
        off[N] = bsum[nb];
    }
}

// packed edge records: cpack[p] = {src, bits(dinv[src]*dinv[dst])}
__global__ void k_fill(const int* __restrict__ src, const int* __restrict__ dst,
                       const float* __restrict__ dinv, const int* __restrict__ off,
                       int* __restrict__ cursor, int2* __restrict__ cpack, int E) {
    int i = blockIdx.x * 256 + threadIdx.x;
    if (i >= E) return;
    int d = dst[i], s = src[i];
    int p = off[d] + atomicAdd(&cursor[d], 1);
    int2 rec; rec.x = s; rec.y = __float_as_int(dinv[s] * dinv[d]);
    cpack[p] = rec;
}

// ---------------- aggregation (R9/R11 structure, cpack metadata) ----------------

template <int F, typename T>
__device__ __forceinline__ void agg_body(
        const T* __restrict__ Hin, const float* __restrict__ dinv,
        const int* __restrict__ off, const int2* __restrict__ cpack,
        unsigned short* __restrict__ out, int N) {
    constexpr int R = (F >= 256) ? 4 : (F >= 128 ? 2 : 1);
    int wave = (int)((blockIdx.x * 256u + threadIdx.x) >> 6);
    int lane = threadIdx.x & 63;
    if (wave >= N) return;
    int fb = (F >= 64) ? lane * R : lane;
    bool act = fb < F;
    int s0 = off[wave], s1 = off[wave + 1];
    float dn = dinv[wave], sn = dn * dn;
    float acc[R];
    #pragma unroll
    for (int j = 0; j < R; ++j) acc[j] = 0.f;
    if (act) {
        const T* ps = Hin + (size_t)wave * F + fb;
        if constexpr (std::is_same_v<T, float>) {
            acc[0] = ps[0] * sn;
        } else if constexpr (R == 4) {
            ushort4 hv = *(const ushort4*)ps;
            acc[0] = bf2f(hv.x) * sn; acc[1] = bf2f(hv.y) * sn;
            acc[2] = bf2f(hv.z) * sn; acc[3] = bf2f(hv.w) * sn;
        } else {
            ushort2 hv = *(const ushort2*)ps;
            acc[0] = bf2f(hv.x) * sn; acc[1] = bf2f(hv.y) * sn;
        }
    }
    int last = s1 - 1;
    for (int e = s0; e < s1; e += 8) {
        int   idx[8];
        float wgt[8];
        #pragma unroll
        for (int j = 0; j < 8; ++j) {
            int ee = e + j;
            int ec = ee <= last ? ee : last;
            int2 m = cpack[ec];
            idx[j] = m.x;
            wgt[j] = (ee <= last) ? __int_as_float(m.y) : 0.f;
        }
        if (act) {
            if constexpr (std::is_same_v<T, float>) {
                float d0[8];
                #pragma unroll
                for (int j = 0; j < 8; ++j) d0[j] = Hin[(size_t)idx[j] * F + fb];
                #pragma unroll
                for (int j = 0; j < 8; ++j) acc[0] += d0[j] * wgt[j];
            } else if constexpr (R == 4) {
                ushort4 d0[8];
                #pragma unroll
                for (int j = 0; j < 8; ++j)
                    d0[j] = *(const ushort4*)(Hin + (size_t)idx[j] * F + fb);
                #pragma unroll
                for (int j = 0; j < 8; ++j) {
                    float w = wgt[j];
                    acc[0] += bf2f(d0[j].x) * w; acc[1] += bf2f(d0[j].y) * w;
                    acc[2] += bf2f(d0[j].z) * w; acc[3] += bf2f(d0[j].w) * w;
                }
            } else {
                ushort2 d0[8];
                #pragma unroll
                for (int j = 0; j < 8; ++j)
                    d0[j] = *(const ushort2*)(Hin + (size_t)idx[j] * F + fb);
                #pragma unroll
                for (int j = 0; j < 8; ++j) {
                    float w = wgt[j];
                    acc[0] += bf2f(d0[j].x) * w; acc[1] += bf2f(d0[j].y) * w;
                }
            }
        }
    }
    if (act) {
        unsigned short* pd = out + (size_t)wave * F + fb;
        if constexpr (R == 4) {
            ushort4 o; o.x = f2bf(acc[0]); o.y = f2bf(acc[1]);
            o.z = f2bf(acc[2]); o.w = f2bf(acc[3]);
            *(ushort4*)pd = o;
        } else if constexpr (R == 2) {
            ushort2 o; o.x = f2bf(acc[0]); o.y = f2bf(acc[1]);
            *(ushort2*)pd = o;
        } else {
            pd[0] = f2bf(acc[0]);
        }
    }
}

__global__ __launch_bounds__(256) void k_aggL1(
        const float* __restrict__ Hin, const float* __restrict__ dinv,
        const int* __restrict__ off, const int2* __restrict__ cpack,
        unsigned short* __restrict__ out, int N) {
    agg_body<32, float>(Hin, dinv, off, cpack, out, N);
}

__global__ __launch_bounds__(256) void k_aggL2(
        const unsigned short* __restrict__ Hin, const float* __restrict__ dinv,
        const int* __restrict__ off, const int2* __restrict__ cpack,
        unsigned short* __restrict__ out, int N) {
    agg_body<128, unsigned short>(Hin, dinv, off, cpack, out, N);
}

__global__ __launch_bounds__(256) void k_aggL3pair(
        const unsigned short* __restrict__ Hin, const float* __restrict__ dinv,
        const int* __restrict__ off, const int2* __restrict__ cpack,
        unsigned short* __restrict__ out, int N) {
    constexpr int F = 256;
    int wave = (int)((blockIdx.x * 256u + threadIdx.x) >> 6);
    int lane = threadIdx.x & 63;
    if (wave >= N) return;
    int half = lane >> 5;
    int fb = (lane & 31) * 8;
    int s0 = off[wave], s1 = off[wave + 1];
    int last = s1 - 1;
    float acc[8];
    #pragma unroll
    for (int k = 0; k < 8; ++k) acc[k] = 0.f;

    for (int e = s0; e < s1; e += 16) {
        int   idx[8];
        float wgt[8];
        #pragma unroll
        for (int j = 0; j < 8; ++j) {
            int ee = e + j * 2 + half;
            int ec = ee <= last ? ee : last;
            int2 m = cpack[ec];
            idx[j] = m.x;
            wgt[j] = (ee <= last) ? __int_as_float(m.y) : 0.f;
        }
        short8 d0[8];
        #pragma unroll
        for (int j = 0; j < 8; ++j)
            d0[j] = *(const short8*)(Hin + (size_t)idx[j] * F + fb);
        #pragma unroll
        for (int j = 0; j < 8; ++j) {
            float w = wgt[j];
            #pragma unroll
            for (int k = 0; k < 8; ++k)
                acc[k] += bf2f((unsigned short)d0[j][k]) * w;
        }
    }
    #pragma unroll
    for (int k = 0; k < 8; ++k) acc[k] += __shfl_xor(acc[k], 32, 64);

    if (half == 0) {
        float dn = dinv[wave], sn = dn * dn;
        short8 selfv = *(const short8*)(Hin + (size_t)wave * F + fb);
        short8 o;
        #pragma unroll
        for (int k = 0; k < 8; ++k)
            o[k] = (short)f2bf(acc[k] + bf2f((unsigned short)selfv[k]) * sn);
        *(short8*)(out + (size_t)wave * F + fb) = o;
    }
}

// ---------------- MFMA GEMM (R17-proven): LDS-staged A (swizzled), coalesced B ----

template <int K, int NC, int POOL>
__device__ __forceinline__ void gemm_body(
        const unsigned short* __restrict__ A, const unsigned short* __restrict__ Wf,
        const float* __restrict__ bias, unsigned short* __restrict__ C,
        float* __restrict__ pooled, const int* __restrict__ batch, int M) {
    constexpr int S = K / 16;
    constexpr int CPR = K / 8;
    constexpr int NT = NC / 32;
    __shared__ unsigned short sA[64 * K];
    __shared__ float pacc[POOL ? 2 : 1][POOL ? NC : 1];
    __shared__ int sbat[POOL ? 64 : 1];
    int tid = threadIdx.x, lane = tid & 63, w = tid >> 6;
    int q = lane >> 5, m = lane & 31;
    int row0 = blockIdx.x * 64;

    if (POOL) {
        if (tid < 64) { int rr = row0 + tid; if (rr > M - 1) rr = M - 1; sbat[tid] = batch[rr]; }
        for (int i = tid; i < 2 * NC; i += 256) pacc[i / NC][i % NC] = 0.f;
    }

    #pragma unroll
    for (int i = 0; i < (64 * CPR) / 256; ++i) {
        int g = i * 256 + tid;
        int mm = g / CPR, kc = g % CPR;
        int grow = row0 + mm; if (grow > M - 1) grow = M - 1;
        short8 v = *(const short8*)(A + (size_t)grow * K + kc * 8);
        int xm = (CPR >= 8) ? (mm & 7) : ((mm >> 1) & 3);
        *(short8*)(sA + (size_t)(mm * CPR + (kc ^ xm)) * 8) = v;
    }
    __syncthreads();

    int gmin = 0; bool fast = false;
    if (POOL) { gmin = sbat[0]; fast = (sbat[63] - gmin) <= 1; }

    const short8* Wf8 = (const short8*)Wf;
    for (int t = w; t < NT; t += 4) {
        short8 bF[S];
        #pragma unroll
        for (int s = 0; s < S; ++s) bF[s] = Wf8[(t * S + s) * 64 + lane];
        int colBase = t * 32 + m;
        float bv = bias[colBase];
        #pragma unroll
        for (int half = 0; half < 2; ++half) {
            int mrow = half * 32 + m;
            int xm = (CPR >= 8) ? (mrow & 7) : ((mrow >> 1) & 3);
            f32x16 acc;
            #pragma unroll
            for (int j = 0; j < 16; ++j) acc[j] = 0.f;
            #pragma unroll
            for (int s = 0; s < S; ++s) {
                int kc = s * 2 + q;
                short8 aF = *(const short8*)(sA + (size_t)(mrow * CPR + (kc ^ xm)) * 8);
                acc = __builtin_amdgcn_mfma_f32_32x32x16_bf16(aF, bF[s], acc, 0, 0, 0);
            }
            #pragma unroll
            for (int j = 0; j < 16; ++j) {
                int rloc = half * 32 + (j & 3) + 8 * (j >> 2) + 4 * q;
                int row = row0 + rloc;
                if (row < M) {
                    float v = fmaxf(acc[j] + bv, 0.f);
                    if (POOL) {
                        int g = sbat[rloc];
                        if (fast) atomicAdd(&pacc[g - gmin][colBase], v);
                        else      atomicAdd(&pooled[(size_t)g * NC + colBase], v);
                    } else {
                        C[(size_t)row * NC + colBase] = f2bf(v);
                    }
                }
            }
        }
    }
    if (POOL) {
        __syncthreads();
        if (fast) {
            for (int i = tid; i < 2 * NC; i += 256) {
                int gg = i / NC, cl = i % NC;
                if (gmin + gg < 64)
                    atomicAdd(&pooled[(size_t)(gmin + gg) * NC + cl], pacc[gg][cl]);
            }
        }
    }
}

__global__ __launch_bounds__(256, 2) void k_gemmL1(
        const unsigned short* __restrict__ A, const unsigned short* __restrict__ Wf,
        const float* __restrict__ bias, unsigned short* __restrict__ C, int M) {
    gemm_body<32, 128, 0>(A, Wf, bias, C, nullptr, nullptr, M);
}

__global__ __launch_bounds__(256, 2) void k_gemmL2(
        const unsigned short* __restrict__ A, const unsigned short* __restrict__ Wf,
        const float* __restrict__ bias, unsigned short* __restrict__ C, int M) {
    gemm_body<128, 256, 0>(A, Wf, bias, C, nullptr, nullptr, M);
}

__global__ __launch_bounds__(256, 2) void k_gemmL3pool(
        const unsigned short* __restrict__ A, const unsigned short* __restrict__ Wf,
        const float* __restrict__ bias, float* __restrict__ pooled,
        const int* __restrict__ batch, int M) {
    gemm_body<256, 512, 1>(A, Wf, bias, nullptr, pooled, batch, M);
}

// ---------------- fused head (R17-proven: runtime-loop dotf, modest VGPR) ----------
// r18 lesson: fully-unrolled dotT<512> -> 256 VGPRs, occupancy collapse, 340 us.

__device__ __forceinline__ float dotf(const float* __restrict__ w,
                                      const float* __restrict__ x, int K) {
    float a = 0.f;
    for (int k = 0; k < K; k += 4) {
        float4 wv = *(const float4*)(w + k);
        a += wv.x * x[k] + wv.y * x[k + 1] + wv.z * x[k + 2] + wv.w * x[k + 3];
    }
    return a;
}

__global__ __launch_bounds__(256) void k_head(
        const float* __restrict__ pooledSum,
        const int* __restrict__ gstart, const int* __restrict__ gend,
        const float* __restrict__ Wih0, const float* __restrict__ bih0,
        const float* __restrict__ bhh0,
        const float* __restrict__ Wih1, const float* __restrict__ bih1,
        const float* __restrict__ bhh1,
        const float* __restrict__ Wp, const float* __restrict__ bp,
        float* __restrict__ out) {
    __shared__ float sx[512];
    __shared__ float sh[256];
    int g = blockIdx.x, tid = threadIdx.x;
    float cnt = (float)(gend[g] - gstart[g]);
    float inv = 1.f / fmaxf(cnt, 1.f);
    sx[tid]       = pooledSum[g * 512 + tid] * inv;
    sx[tid + 256] = pooledSum[g * 512 + 256 + tid] * inv;
    __syncthreads();

    float ai = bih0[tid]       + bhh0[tid];
    float ag = bih0[tid + 512] + bhh0[tid + 512];
    float ao = bih0[tid + 768] + bhh0[tid + 768];
    ai += dotf(Wih0 + (size_t)tid * 512, sx, 512);
    ag += dotf(Wih0 + (size_t)(tid + 512) * 512, sx, 512);
    ao += dotf(Wih0 + (size_t)(tid + 768) * 512, sx, 512);
    float c0 = sigm(ai) * tanhf(ag);
    float h1 = sigm(ao) * tanhf(c0);
    __syncthreads();
    sh[tid] = h1;
    __syncthreads();

    ai = bih1[tid]       + bhh1[tid];
    ag = bih1[tid + 512] + bhh1[tid + 512];
    ao = bih1[tid + 768] + bhh1[tid + 768];
    ai += dotf(Wih1 + (size_t)tid * 256, sh, 256);
    ag += dotf(Wih1 + (size_t)(tid + 512) * 256, sh, 256);
    ao += dotf(Wih1 + (size_t)(tid + 768) * 256, sh, 256);
    float c1 = sigm(ai) * tanhf(ag);
    float h2 = sigm(ao) * tanhf(c1);
    __syncthreads();
    sx[tid] = h2;
    __syncthreads();

    float o0 = bp[tid]       + dotf(Wp + (size_t)tid * 256, sx, 256);
    float o1 = bp[tid + 256] + dotf(Wp + (size_t)(tid + 256) * 256, sx, 256);
    out[g * 512 + tid]       = o0;
    out[g * 512 + 256 + tid] = o1;
}

// ---------------- launch ----------------

extern "C" void kernel_launch(void* const* d_in, const int* in_sizes, int n_in,
                              void* d_out, int out_size, void* d_ws, size_t ws_size,
                              hipStream_t stream) {
    const float* x     = (const float*)d_in[0];
    const int*   eidx  = (const int*)d_in[1];
    const int*   batch = (const int*)d_in[2];
    const float* W1 = (const float*)d_in[3];  const float* b1 = (const float*)d_in[4];
    const float* W2 = (const float*)d_in[5];  const float* b2 = (const float*)d_in[6];
    const float* W3 = (const float*)d_in[7];  const float* b3 = (const float*)d_in[8];
    const float* Wih0 = (const float*)d_in[9];
    const float* bih0 = (const float*)d_in[11];
    const float* bhh0 = (const float*)d_in[12];
    const float* Wih1 = (const float*)d_in[13];
    const float* bih1 = (const float*)d_in[15];
    const float* bhh1 = (const float*)d_in[16];
    const float* Wp = (const float*)d_in[17]; const float* bp = (const float*)d_in[18];
    float* out = (float*)d_out;

    const int N = in_sizes[0] / 32;
    const int E = in_sizes[1] / 2;
    const int* src = eidx;
    const int* dst = eidx + E;
    const int rowTiles = (N + 63) / 64;

    char* w = (char*)d_ws;
    auto alloc = [&](size_t bytes) {
        char* p = w;
        w += (bytes + 255) & ~(size_t)255;
        return p;
    };
    unsigned short* buf1 = (unsigned short*)alloc((size_t)N * 256 * 2);
    unsigned short* buf2 = (unsigned short*)alloc((size_t)N * 256 * 2);
    unsigned short* Wf1  = (unsigned short*)alloc(128 * 32 * 2);
    unsigned short* Wf2  = (unsigned short*)alloc(256 * 128 * 2);
    unsigned short* Wf3  = (unsigned short*)alloc(512 * 256 * 2);
    int*   indeg  = (int*)alloc((size_t)N * 4);
    int*   off    = (int*)alloc((size_t)(N + 1) * 4);
    int*   cursor = (int*)alloc((size_t)N * 4);
    float* dinv   = (float*)alloc((size_t)N * 4);
    int2*  cpack  = (int2*)alloc((size_t)E * 8);
    int*   bsum   = (int*)alloc(300 * 4);
    int*   gstart = (int*)alloc(64 * 4);
    int*   gend   = (int*)alloc(64 * 4);
    float* pooled = (float*)alloc(64 * 512 * 4);

    int initTot = 2 * N + 128 + 64 * 512;
    k_init<<<(initTot + 255) / 256, 256, 0, stream>>>(indeg, cursor, gstart, gend, pooled, N);
    k_count<<<(E + 255) / 256, 256, 0, stream>>>(dst, indeg, E, W1, Wf1, W2, Wf2, W3, Wf3);
    int nb = (N + 1023) / 1024;
    k_scan1<<<nb, 1024, 0, stream>>>(indeg, off, bsum, dinv, N);
    k_scan2<<<1, 256, 0, stream>>>(bsum, nb);
    k_scan3<<<(N + 1 + 1023) / 1024, 1024, 0, stream>>>(off, bsum, batch, gstart, gend, N, nb);
    k_fill<<<(E + 255) / 256, 256, 0, stream>>>(src, dst, dinv, off, cursor, cpack, E);

    int aggBlocks = (N + 3) / 4;

    k_aggL1<<<aggBlocks, 256, 0, stream>>>(x, dinv, off, cpack, buf1, N);
    k_gemmL1<<<rowTiles, 256, 0, stream>>>(buf1, Wf1, b1, buf2, N);
    k_aggL2<<<aggBlocks, 256, 0, stream>>>(buf2, dinv, off, cpack, buf1, N);
    k_gemmL2<<<rowTiles, 256, 0, stream>>>(buf1, Wf2, b2, buf2, N);
    k_aggL3pair<<<aggBlocks, 256, 0, stream>>>(buf2, dinv, off, cpack, buf1, N);
    k_gemmL3pool<<<rowTiles, 256, 0, stream>>>(buf1, Wf3, b3, pooled, batch, N);

    k_head<<<64, 256, 0, stream>>>(pooled, gstart, gend,
                                   Wih0, bih0, bhh0, Wih1, bih1, bhh1, Wp, bp, out);
}

// Round 20
// 795.384 us; speedup vs baseline: 1.2100x; 1.0343x over previous
//
#include <hip/hip_runtime.h>
#include <math.h>
#include <type_traits>

// ---------- bf16 helpers (intermediate buffers only; I/O is fp32) ----------

__device__ __forceinline__ float bf2f(unsigned short u) {
    union { unsigned int i; float f; } v; v.i = ((unsigned int)u) << 16; return v.f;
}
__device__ __forceinline__ unsigned short f2bf(float f) {
    union { float f_; unsigned int i; } v; v.f_ = f;
    unsigned int x = v.i;
    return (unsigned short)((x + 0x7fffu + ((x >> 16) & 1u)) >> 16);  // RNE
}
__device__ __forceinline__ float sigm(float x) { return 1.f / (1.f + expf(-x)); }

typedef __attribute__((ext_vector_type(8))) short short8;
typedef __attribute__((ext_vector_type(16))) float f32x16;

// ---------------- fused init ----------------

__global__ void k_init(int* __restrict__ indeg, int* __restrict__ cursor,
                       int* __restrict__ gstart, int* __restrict__ gend,
                       float* __restrict__ pooled, int N) {
    int i = blockIdx.x * 256 + threadIdx.x;
    if (i < N) indeg[i] = 0;
    else if (i < 2 * N) cursor[i - N] = 0;
    else if (i < 2 * N + 64) gstart[i - 2 * N] = 0;
    else if (i < 2 * N + 128) gend[i - 2 * N - 64] = 0;
    else if (i < 2 * N + 128 + 64 * 512) pooled[i - 2 * N - 128] = 0.f;
}

// ---------------- weight prep: fragment-major Wf for 32x32x16 MFMA ----------------

template <int K, int NC>
__device__ __forceinline__ void prep_elem(const float* __restrict__ W,
                                          unsigned short* __restrict__ Wf, int idx) {
    constexpr int S = K / 16;
    int lane = idx & 63;
    int ts = idx >> 6;
    int s = ts % S, t = ts / S;
    int n = t * 32 + (lane & 31);
    int kb = s * 16 + (lane >> 5) * 8;
    short8 o;
    #pragma unroll
    for (int j = 0; j < 8; ++j) o[j] = (short)f2bf(W[(size_t)(kb + j) * NC + n]);
    *(short8*)(Wf + (size_t)idx * 8) = o;
}

__global__ void k_count(const int* __restrict__ dst, int* __restrict__ indeg, int E,
                        const float* __restrict__ W1, unsigned short* __restrict__ Wf1,
                        const float* __restrict__ W2, unsigned short* __restrict__ Wf2,
                        const float* __restrict__ W3, unsigned short* __restrict__ Wf3) {
    constexpr int P1 = 32 * 128 / 8, P2 = 128 * 256 / 8, P3 = 256 * 512 / 8;
    int i = blockIdx.x * 256 + threadIdx.x;
    if (i < E) atomicAdd(&indeg[dst[i]], 1);
    if (i < P1) prep_elem<32, 128>(W1, Wf1, i);
    else if (i < P1 + P2) prep_elem<128, 256>(W2, Wf2, i - P1);
    else if (i < P1 + P2 + P3) prep_elem<256, 512>(W3, Wf3, i - P1 - P2);
}

// ---------------- scan + dinv / + bounds ----------------

__global__ __launch_bounds__(1024) void k_scan1(const int* __restrict__ in, int* __restrict__ out,
                                                int* __restrict__ bsum, float* __restrict__ dinv,
                                                int N) {
    __shared__ int sd[1024];
    int tid = threadIdx.x;
    int i = blockIdx.x * 1024 + tid;
    int v = (i < N) ? in[i] : 0;
    if (i < N) dinv[i] = rsqrtf((float)v + 1.0f);
    sd[tid] = v;
    __syncthreads();
    for (int s = 1; s < 1024; s <<= 1) {
        int t = (tid >= s) ? sd[tid - s] : 0;
        __syncthreads();
        sd[tid] += t;
        __syncthreads();
    }
    if (i < N) out[i] = sd[tid] - v;
    if (tid == 1023) bsum[blockIdx.x] = sd[1023];
}

// parallel block-sum scan (nb <= 256)
__global__ __launch_bounds__(256) void k_scan2(int* __restrict__ bsum, int nb) {
    __shared__ int sd[256];
    int tid = threadIdx.x;
    int v = (tid < nb) ? bsum[tid] : 0;
    sd[tid] = v;
    __syncthreads();
    for (int s = 1; s < 256; s <<= 1) {
        int t = (tid >= s) ? sd[tid - s] : 0;
        __syncthreads();
        sd[tid] += t;
        __syncthreads();
    }
    if (tid < nb) bsum[tid] = sd[tid] - v;   // exclusive
    if (tid == 0) bsum[nb] = sd[255];        // total
}

__global__ __launch_bounds__(1024) void k_scan3(int* __restrict__ off, const int* __restrict__ bsum,
                                                const int* __restrict__ batch,
                                                int* __restrict__ gstart, int* __restrict__ gend,
                                                int N, int nb) {
    int i = blockIdx.x * 1024 + threadIdx.x;
    if (i < N) {
        off[i] += bsum[i >> 10];
        int g = batch[i];
        if (i == 0 || batch[i - 1] != g) gstart[g] = i;
        if (i == N - 1 || batch[i + 1] != g) gend[g] = i + 1;
    } else if (i == N) {
        off[N] = bsum[nb];
    }
}

// separate csrc/cw arrays (R17-proven; cpack int2 packing measured +17 us twice)
__global__ void k_fill(const int* __restrict__ src, const int* __restrict__ dst,
                       const float* __restrict__ dinv, const int* __restrict__ off,
                       int* __restrict__ cursor, int* __restrict__ csrc,
                       float* __restrict__ cw, int E) {
    int i = blockIdx.x * 256 + threadIdx.x;
    if (i >= E) return;
    int d = dst[i], s = src[i];
    int p = off[d] + atomicAdd(&cursor[d], 1);
    csrc[p] = s;
    cw[p] = dinv[s] * dinv[d];
}

// ---------------- aggregation (R9/R11-proven) ----------------

template <int F, typename T>
__device__ __forceinline__ void agg_body(
        const T* __restrict__ Hin, const float* __restrict__ dinv,
        const int* __restrict__ off, const int* __restrict__ csrc,
        const float* __restrict__ cw, unsigned short* __restrict__ out, int N) {
    constexpr int R = (F >= 256) ? 4 : (F >= 128 ? 2 : 1);
    int wave = (int)((blockIdx.x * 256u + threadIdx.x) >> 6);
    int lane = threadIdx.x & 63;
    if (wave >= N) return;
    int fb = (F >= 64) ? lane * R : lane;
    bool act = fb < F;
    int s0 = off[wave], s1 = off[wave + 1];
    float dn = dinv[wave], sn = dn * dn;
    float acc[R];
    #pragma unroll
    for (int j = 0; j < R; ++j) acc[j] = 0.f;
    if (act) {
        const T* ps = Hin + (size_t)wave * F + fb;
        if constexpr (std::is_same_v<T, float>) {
            acc[0] = ps[0] * sn;
        } else if constexpr (R == 4) {
            ushort4 hv = *(const ushort4*)ps;
            acc[0] = bf2f(hv.x) * sn; acc[1] = bf2f(hv.y) * sn;
            acc[2] = bf2f(hv.z) * sn; acc[3] = bf2f(hv.w) * sn;
        } else {
            ushort2 hv = *(const ushort2*)ps;
            acc[0] = bf2f(hv.x) * sn; acc[1] = bf2f(hv.y) * sn;
        }
    }
    int last = s1 - 1;
    for (int e = s0; e < s1; e += 8) {
        int   idx[8];
        float wgt[8];
        #pragma unroll
        for (int j = 0; j < 8; ++j) {
            int ee = e + j;
            int ec = ee <= last ? ee : last;
            idx[j] = csrc[ec];
            wgt[j] = (ee <= last) ? cw[ec] : 0.f;
        }
        if (act) {
            if constexpr (std::is_same_v<T, float>) {
                float d0[8];
                #pragma unroll
                for (int j = 0; j < 8; ++j) d0[j] = Hin[(size_t)idx[j] * F + fb];
                #pragma unroll
                for (int j = 0; j < 8; ++j) acc[0] += d0[j] * wgt[j];
            } else if constexpr (R == 4) {
                ushort4 d0[8];
                #pragma unroll
                for (int j = 0; j < 8; ++j)
                    d0[j] = *(const ushort4*)(Hin + (size_t)idx[j] * F + fb);
                #pragma unroll
                for (int j = 0; j < 8; ++j) {
                    float w = wgt[j];
                    acc[0] += bf2f(d0[j].x) * w; acc[1] += bf2f(d0[j].y) * w;
                    acc[2] += bf2f(d0[j].z) * w; acc[3] += bf2f(d0[j].w) * w;
                }
            } else {
                ushort2 d0[8];
                #pragma unroll
                for (int j = 0; j < 8; ++j)
                    d0[j] = *(const ushort2*)(Hin + (size_t)idx[j] * F + fb);
                #pragma unroll
                for (int j = 0; j < 8; ++j) {
                    float w = wgt[j];
                    acc[0] += bf2f(d0[j].x) * w; acc[1] += bf2f(d0[j].y) * w;
                }
            }
        }
    }
    if (act) {
        unsigned short* pd = out + (size_t)wave * F + fb;
        if constexpr (R == 4) {
            ushort4 o; o.x = f2bf(acc[0]); o.y = f2bf(acc[1]);
            o.z = f2bf(acc[2]); o.w = f2bf(acc[3]);
            *(ushort4*)pd = o;
        } else if constexpr (R == 2) {
            ushort2 o; o.x = f2bf(acc[0]); o.y = f2bf(acc[1]);
            *(ushort2*)pd = o;
        } else {
            pd[0] = f2bf(acc[0]);
        }
    }
}

__global__ __launch_bounds__(256) void k_aggL1(
        const float* __restrict__ Hin, const float* __restrict__ dinv,
        const int* __restrict__ off, const int* __restrict__ csrc,
        const float* __restrict__ cw, unsigned short* __restrict__ out, int N) {
    agg_body<32, float>(Hin, dinv, off, csrc, cw, out, N);
}

__global__ __launch_bounds__(256) void k_aggL2(
        const unsigned short* __restrict__ Hin, const float* __restrict__ dinv,
        const int* __restrict__ off, const int* __restrict__ csrc,
        const float* __restrict__ cw, unsigned short* __restrict__ out, int N) {
    agg_body<128, unsigned short>(Hin, dinv, off, csrc, cw, out, N);
}

__global__ __launch_bounds__(256) void k_aggL3pair(
        const unsigned short* __restrict__ Hin, const float* __restrict__ dinv,
        const int* __restrict__ off, const int* __restrict__ csrc,
        const float* __restrict__ cw, unsigned short* __restrict__ out, int N) {
    constexpr int F = 256;
    int wave = (int)((blockIdx.x * 256u + threadIdx.x) >> 6);
    int lane = threadIdx.x & 63;
    if (wave >= N) return;
    int half = lane >> 5;
    int fb = (lane & 31) * 8;
    int s0 = off[wave], s1 = off[wave + 1];
    int last = s1 - 1;
    float acc[8];
    #pragma unroll
    for (int k = 0; k < 8; ++k) acc[k] = 0.f;

    for (int e = s0; e < s1; e += 16) {
        int   idx[8];
        float wgt[8];
        #pragma unroll
        for (int j = 0; j < 8; ++j) {
            int ee = e + j * 2 + half;
            int ec = ee <= last ? ee : last;
            idx[j] = csrc[ec];
            wgt[j] = (ee <= last) ? cw[ec] : 0.f;
        }
        short8 d0[8];
        #pragma unroll
        for (int j = 0; j < 8; ++j)
            d0[j] = *(const short8*)(Hin + (size_t)idx[j] * F + fb);
        #pragma unroll
        for (int j = 0; j < 8; ++j) {
            float w = wgt[j];
            #pragma unroll
            for (int k = 0; k < 8; ++k)
                acc[k] += bf2f((unsigned short)d0[j][k]) * w;
        }
    }
    #pragma unroll
    for (int k = 0; k < 8; ++k) acc[k] += __shfl_xor(acc[k], 32, 64);

    if (half == 0) {
        float dn = dinv[wave], sn = dn * dn;
        short8 selfv = *(const short8*)(Hin + (size_t)wave * F + fb);
        short8 o;
        #pragma unroll
        for (int k = 0; k < 8; ++k)
            o[k] = (short)f2bf(acc[k] + bf2f((unsigned short)selfv[k]) * sn);
        *(short8*)(out + (size_t)wave * F + fb) = o;
    }
}

// ---------------- MFMA GEMM (R17-proven): LDS-staged A (swizzled), coalesced B ----

template <int K, int NC, int POOL>
__device__ __forceinline__ void gemm_body(
        const unsigned short* __restrict__ A, const unsigned short* __restrict__ Wf,
        const float* __restrict__ bias, unsigned short* __restrict__ C,
        float* __restrict__ pooled, const int* __restrict__ batch, int M) {
    constexpr int S = K / 16;
    constexpr int CPR = K / 8;
    constexpr int NT = NC / 32;
    __shared__ unsigned short sA[64 * K];
    __shared__ float pacc[POOL ? 2 : 1][POOL ? NC : 1];
    __shared__ int sbat[POOL ? 64 : 1];
    int tid = threadIdx.x, lane = tid & 63, w = tid >> 6;
    int q = lane >> 5, m = lane & 31;
    int row0 = blockIdx.x * 64;

    if (POOL) {
        if (tid < 64) { int rr = row0 + tid; if (rr > M - 1) rr = M - 1; sbat[tid] = batch[rr]; }
        for (int i = tid; i < 2 * NC; i += 256) pacc[i / NC][i % NC] = 0.f;
    }

    #pragma unroll
    for (int i = 0; i < (64 * CPR) / 256; ++i) {
        int g = i * 256 + tid;
        int mm = g / CPR, kc = g % CPR;
        int grow = row0 + mm; if (grow > M - 1) grow = M - 1;
        short8 v = *(const short8*)(A + (size_t)grow * K + kc * 8);
        int xm = (CPR >= 8) ? (mm & 7) : ((mm >> 1) & 3);
        *(short8*)(sA + (size_t)(mm * CPR + (kc ^ xm)) * 8) = v;
    }
    __syncthreads();

    int gmin = 0; bool fast = false;
    if (POOL) { gmin = sbat[0]; fast = (sbat[63] - gmin) <= 1; }

    const short8* Wf8 = (const short8*)Wf;
    for (int t = w; t < NT; t += 4) {
        short8 bF[S];
        #pragma unroll
        for (int s = 0; s < S; ++s) bF[s] = Wf8[(t * S + s) * 64 + lane];
        int colBase = t * 32 + m;
        float bv = bias[colBase];
        #pragma unroll
        for (int half = 0; half < 2; ++half) {
            int mrow = half * 32 + m;
            int xm = (CPR >= 8) ? (mrow & 7) : ((mrow >> 1) & 3);
            f32x16 acc;
            #pragma unroll
            for (int j = 0; j < 16; ++j) acc[j] = 0.f;
            #pragma unroll
            for (int s = 0; s < S; ++s) {
                int kc = s * 2 + q;
                short8 aF = *(const short8*)(sA + (size_t)(mrow * CPR + (kc ^ xm)) * 8);
                acc = __builtin_amdgcn_mfma_f32_32x32x16_bf16(aF, bF[s], acc, 0, 0, 0);
            }
            #pragma unroll
            for (int j = 0; j < 16; ++j) {
                int rloc = half * 32 + (j & 3) + 8 * (j >> 2) + 4 * q;
                int row = row0 + rloc;
                if (row < M) {
                    float v = fmaxf(acc[j] + bv, 0.f);
                    if (POOL) {
                        int g = sbat[rloc];
                        if (fast) atomicAdd(&pacc[g - gmin][colBase], v);
                        else      atomicAdd(&pooled[(size_t)g * NC + colBase], v);
                    } else {
                        C[(size_t)row * NC + colBase] = f2bf(v);
                    }
                }
            }
        }
    }
    if (POOL) {
        __syncthreads();
        if (fast) {
            for (int i = tid; i < 2 * NC; i += 256) {
                int gg = i / NC, cl = i % NC;
                if (gmin + gg < 64)
                    atomicAdd(&pooled[(size_t)(gmin + gg) * NC + cl], pacc[gg][cl]);
            }
        }
    }
}

__global__ __launch_bounds__(256, 2) void k_gemmL1(
        const unsigned short* __restrict__ A, const unsigned short* __restrict__ Wf,
        const float* __restrict__ bias, unsigned short* __restrict__ C, int M) {
    gemm_body<32, 128, 0>(A, Wf, bias, C, nullptr, nullptr, M);
}

__global__ __launch_bounds__(256, 2) void k_gemmL2(
        const unsigned short* __restrict__ A, const unsigned short* __restrict__ Wf,
        const float* __restrict__ bias, unsigned short* __restrict__ C, int M) {
    gemm_body<128, 256, 0>(A, Wf, bias, C, nullptr, nullptr, M);
}

__global__ __launch_bounds__(256, 2) void k_gemmL3pool(
        const unsigned short* __restrict__ A, const unsigned short* __restrict__ Wf,
        const float* __restrict__ bias, float* __restrict__ pooled,
        const int* __restrict__ batch, int M) {
    gemm_body<256, 512, 1>(A, Wf, bias, nullptr, pooled, batch, M);
}

// ---------------- fused head (R17-proven: runtime-loop dotf, modest VGPR) ----------

__device__ __forceinline__ float dotf(const float* __restrict__ w,
                                      const float* __restrict__ x, int K) {
    float a = 0.f;
    for (int k = 0; k < K; k += 4) {
        float4 wv = *(const float4*)(w + k);
        a += wv.x * x[k] + wv.y * x[k + 1] + wv.z * x[k + 2] + wv.w * x[k + 3];
    }
    return a;
}

__global__ __launch_bounds__(256) void k_head(
        const float* __restrict__ pooledSum,
        const int* __restrict__ gstart, const int* __restrict__ gend,
        const float* __restrict__ Wih0, const float* __restrict__ bih0,
        const float* __restrict__ bhh0,
        const float* __restrict__ Wih1, const float* __restrict__ bih1,
        const float* __restrict__ bhh1,
        const float* __restrict__ Wp, const float* __restrict__ bp,
        float* __restrict__ out) {
    __shared__ float sx[512];
    __shared__ float sh[256];
    int g = blockIdx.x, tid = threadIdx.x;
    float cnt = (float)(gend[g] - gstart[g]);
    float inv = 1.f / fmaxf(cnt, 1.f);
    sx[tid]       = pooledSum[g * 512 + tid] * inv;
    sx[tid + 256] = pooledSum[g * 512 + 256 + tid] * inv;
    __syncthreads();

    float ai = bih0[tid]       + bhh0[tid];
    float ag = bih0[tid + 512] + bhh0[tid + 512];
    float ao = bih0[tid + 768] + bhh0[tid + 768];
    ai += dotf(Wih0 + (size_t)tid * 512, sx, 512);
    ag += dotf(Wih0 + (size_t)(tid + 512) * 512, sx, 512);
    ao += dotf(Wih0 + (size_t)(tid + 768) * 512, sx, 512);
    float c0 = sigm(ai) * tanhf(ag);
    float h1 = sigm(ao) * tanhf(c0);
    __syncthreads();
    sh[tid] = h1;
    __syncthreads();

    ai = bih1[tid]       + bhh1[tid];
    ag = bih1[tid + 512] + bhh1[tid + 512];
    ao = bih1[tid + 768] + bhh1[tid + 768];
    ai += dotf(Wih1 + (size_t)tid * 256, sh, 256);
    ag += dotf(Wih1 + (size_t)(tid + 512) * 256, sh, 256);
    ao += dotf(Wih1 + (size_t)(tid + 768) * 256, sh, 256);
    float c1 = sigm(ai) * tanhf(ag);
    float h2 = sigm(ao) * tanhf(c1);
    __syncthreads();
    sx[tid] = h2;
    __syncthreads();

    float o0 = bp[tid]       + dotf(Wp + (size_t)tid * 256, sx, 256);
    float o1 = bp[tid + 256] + dotf(Wp + (size_t)(tid + 256) * 256, sx, 256);
    out[g * 512 + tid]       = o0;
    out[g * 512 + 256 + tid] = o1;
}

// ---------------- launch ----------------

extern "C" void kernel_launch(void* const* d_in, const int* in_sizes, int n_in,
                              void* d_out, int out_size, void* d_ws, size_t ws_size,
                              hipStream_t stream) {
    const float* x     = (const float*)d_in[0];
    const int*   eidx  = (const int*)d_in[1];
    const int*   batch = (const int*)d_in[2];
    const float* W1 = (const float*)d_in[3];  const float* b1 = (const float*)d_in[4];
    const float* W2 = (const float*)d_in[5];  const float* b2 = (const float*)d_in[6];
    const float* W3 = (const float*)d_in[7];  const float* b3 = (const float*)d_in[8];
    const float* Wih0 = (const float*)d_in[9];
    const float* bih0 = (const float*)d_in[11];
    const float* bhh0 = (const float*)d_in[12];
    const float* Wih1 = (const float*)d_in[13];
    const float* bih1 = (const float*)d_in[15];
    const float* bhh1 = (const float*)d_in[16];
    const float* Wp = (const float*)d_in[17]; const float* bp = (const float*)d_in[18];
    float* out = (float*)d_out;

    const int N = in_sizes[0] / 32;
    const int E = in_sizes[1] / 2;
    const int* src = eidx;
    const int* dst = eidx + E;
    const int rowTiles = (N + 63) / 64;

    char* w = (char*)d_ws;
    auto alloc = [&](size_t bytes) {
        char* p = w;
        w += (bytes + 255) & ~(size_t)255;
        return p;
    };
    unsigned short* buf1 = (unsigned short*)alloc((size_t)N * 256 * 2);
    unsigned short* buf2 = (unsigned short*)alloc((size_t)N * 256 * 2);
    unsigned short* Wf1  = (unsigned short*)alloc(128 * 32 * 2);
    unsigned short* Wf2  = (unsigned short*)alloc(256 * 128 * 2);
    unsigned short* Wf3  = (unsigned short*)alloc(512 * 256 * 2);
    int*   indeg  = (int*)alloc((size_t)N * 4);
    int*   off    = (int*)alloc((size_t)(N + 1) * 4);
    int*   cursor = (int*)alloc((size_t)N * 4);
    float* dinv   = (float*)alloc((size_t)N * 4);
    int*   csrc   = (int*)alloc((size_t)E * 4);
    float* cw     = (float*)alloc((size_t)E * 4);
    int*   bsum   = (int*)alloc(300 * 4);
    int*   gstart = (int*)alloc(64 * 4);
    int*   gend   = (int*)alloc(64 * 4);
    float* pooled = (float*)alloc(64 * 512 * 4);

    int initTot = 2 * N + 128 + 64 * 512;
    k_init<<<(initTot + 255) / 256, 256, 0, stream>>>(indeg, cursor, gstart, gend, pooled, N);
    k_count<<<(E + 255) / 256, 256, 0, stream>>>(dst, indeg, E, W1, Wf1, W2, Wf2, W3, Wf3);
    int nb = (N + 1023) / 1024;
    k_scan1<<<nb, 1024, 0, stream>>>(indeg, off, bsum, dinv, N);
    k_scan2<<<1, 256, 0, stream>>>(bsum, nb);
    k_scan3<<<(N + 1 + 1023) / 1024, 1024, 0, stream>>>(off, bsum, batch, gstart, gend, N, nb);
    k_fill<<<(E + 255) / 256, 256, 0, stream>>>(src, dst, dinv, off, cursor, csrc, cw, E);

    int aggBlocks = (N + 3) / 4;

    k_aggL1<<<aggBlocks, 256, 0, stream>>>(x, dinv, off, csrc, cw, buf1, N);
    k_gemmL1<<<rowTiles, 256, 0, stream>>>(buf1, Wf1, b1, buf2, N);
    k_aggL2<<<aggBlocks, 256, 0, stream>>>(buf2, dinv, off, csrc, cw, buf1, N);
    k_gemmL2<<<rowTiles, 256, 0, stream>>>(buf1, Wf2, b2, buf2, N);
    k_aggL3pair<<<aggBlocks, 256, 0, stream>>>(buf2, dinv, off, csrc, cw, buf1, N);
    k_gemmL3pool<<<rowTiles, 256, 0, stream>>>(buf1, Wf3, b3, pooled, batch, N);

    k_head<<<64, 256, 0, stream>>>(pooled, gstart, gend,
                                   Wih0, bih0, bhh0, Wih1, bih1, bhh1, Wp, bp, out);
}